// Round 3
// baseline (2829.546 us; speedup 1.0000x reference)
//
#include <hip/hip_runtime.h>
#include <cmath>

namespace {

constexpr int kWin = 100;
constexpr int kNin = 700;

// Transposed-weight offsets (floats) inside d_ws.
constexpr size_t OFF1 = 0;        // WT1 [700][512]
constexpr size_t OFF2 = 358400;   // WT2 [512][256]
constexpr size_t OFF3 = 489472;   // WT3 [256][128]
constexpr size_t OFF4 = 522240;   // WT4 [128][256]
constexpr size_t OFF5 = 555008;   // WT5 [256][512]
constexpr size_t OFF6 = 686080;   // WT6 [512][700]
constexpr size_t OFF_END = 1044480;          // floats used by weights
constexpr size_t XM_OFF_U64 = OFF_END / 2;   // u64 index into ws for xmasks
// xmask layout: [B=512][T=100][12] u64 words (11 used + 1 pad, always written)

__global__ void transpose_k(const float* __restrict__ src, float* __restrict__ dst,
                            int H, int K) {
  int idx = blockIdx.x * blockDim.x + threadIdx.x;
  if (idx < H * K) {
    int h = idx / K;
    int k = idx - h * K;
    dst[k * H + h] = src[idx];  // dst[K][H] = src[H][K]^T
  }
}

// Build input spike bitmasks: one block per (row, t), 256 threads.
// Word w covers input neurons h in [w*64, w*64+64), bit = h%64.
__global__ __launch_bounds__(256) void xmask_k(const float* __restrict__ x,
                                               unsigned long long* __restrict__ xm) {
  const int bid = blockIdx.x;  // row * 100 + t
  const int tid = threadIdx.x;
  const int lane = tid & 63;
  const int wv = tid >> 6;  // 0..3
  const float* xr = x + (size_t)bid * kNin;
  unsigned long long* dst = xm + (size_t)bid * 12;
#pragma unroll
  for (int s = 0; s < 3; ++s) {
    const int h = s * 256 + tid;
    const bool p = (h < kNin) ? (xr[h] != 0.0f) : false;
    const unsigned long long b = __ballot(p);
    if (lane == 0) dst[s * 4 + wv] = b;  // s=2,wv=3 writes pad word 11 (= 0)
  }
}

// One LIF layer, outputs-direct: thread tid owns output neuron h = tid (h < H).
// Input spike mask (K bits) is preloaded into scalar regs, then bit-walked with
// 4 independent f64 accumulators (order is a fixed deterministic permutation;
// R1->R2 proved f64 ordering noise is far below the spike margin).
// mem_new = mem*alpha + sum(active WT columns); spike = mem_new > 0.3;
// mem = (mem_new < 0.3) ? mem_new : 0.  ((1-o_spike) is redundant: the hard
// reset already zeroed spiking neurons; VRESET = 0.)
template <int K, int H, bool OUT>
__device__ __forceinline__ void lif(const float* __restrict__ WT,
                                    const unsigned* __restrict__ mwIn,  // u32 view
                                    unsigned long long* mkNext,
                                    double& mem, double alpha,
                                    float* __restrict__ outRow,
                                    int tid, int lane, int wv) {
  constexpr int NC = (K + 63) / 64;  // input mask words
  const bool waveOn = (wv * 64 < H);
  if (waveOn) {
    // Preload mask words -> scalar regs (fully unrolled, static indices).
    unsigned long long mloc[NC];
#pragma unroll
    for (int c = 0; c < NC; ++c) {
      const unsigned lo = __builtin_amdgcn_readfirstlane(mwIn[2 * c]);
      const unsigned hi = __builtin_amdgcn_readfirstlane(mwIn[2 * c + 1]);
      mloc[c] = ((unsigned long long)hi << 32) | lo;
    }
    bool sp = false;
    const bool active = (tid < H);
    if (active) {
      double a0 = 0.0, a1 = 0.0, a2 = 0.0, a3 = 0.0;
      const float* __restrict__ cb = WT + tid;
#pragma unroll 1
      for (int c = 0; c < NC; ++c) {
        unsigned long long m = mloc[c];
        const float* __restrict__ cb2 = cb + (size_t)c * 64 * H;
        const int cnt = __popcll(m);
        int i = 0;
        for (; i + 4 <= cnt; i += 4) {
          const int b0 = (int)__builtin_ctzll(m); m &= m - 1;
          const int b1 = (int)__builtin_ctzll(m); m &= m - 1;
          const int b2 = (int)__builtin_ctzll(m); m &= m - 1;
          const int b3 = (int)__builtin_ctzll(m); m &= m - 1;
          const float f0 = cb2[b0 * H];
          const float f1 = cb2[b1 * H];
          const float f2 = cb2[b2 * H];
          const float f3 = cb2[b3 * H];
          a0 += (double)f0;
          a1 += (double)f1;
          a2 += (double)f2;
          a3 += (double)f3;
        }
        for (; i < cnt; ++i) {
          const int b = (int)__builtin_ctzll(m); m &= m - 1;
          a0 += (double)cb2[b * H];
        }
      }
      const double sum = (a0 + a1) + (a2 + a3);
      const double mm = mem * alpha + sum;
      sp = (mm > 0.3);
      mem = (mm < 0.3) ? mm : 0.0;
      if (OUT) outRow[tid] = sp ? 1.0f : 0.0f;
    }
    if (!OUT) {
      // Wave wv covers h in [64wv, 64wv+64) == mask word wv of the next layer.
      const unsigned long long b = __ballot(sp);
      if (lane == 0) mkNext[wv] = b;
    }
  }
  __syncthreads();
}

// 512 blocks x 704 threads (11 waves), one batch row per block. Steps 0..4 of
// the reference (zero-padded input) provably keep all state at 0, so only the
// 100 live steps run. One barrier per layer; masks ping-pong in 192B of LDS.
__global__ __launch_bounds__(704) void snn_main(
    const float* __restrict__ wsf, const unsigned long long* __restrict__ xmask,
    float* __restrict__ out) {
  const int tid = threadIdx.x;
  const int lane = tid & 63;
  const int wv = tid >> 6;
  const int row = blockIdx.x;

  const float* WT1 = wsf + OFF1;
  const float* WT2 = wsf + OFF2;
  const float* WT3 = wsf + OFF3;
  const float* WT4 = wsf + OFF4;
  const float* WT5 = wsf + OFF5;
  const float* WT6 = wsf + OFF6;

  __shared__ unsigned long long mk[2][12];

  // Per-thread membrane state (f64) for h = tid in each layer where tid < H.
  double m1 = 0.0, m2 = 0.0, m3 = 0.0, m4 = 0.0, m5 = 0.0, m6 = 0.0;

  const double alpha = exp(-1.0 / 3.0);

  const unsigned long long* xmRow = xmask + (size_t)row * kWin * 12;
  float* outRowBase = out + (size_t)row * kWin * kNin;

  for (int t = 0; t < kWin; ++t) {
    const unsigned* xm32 = (const unsigned*)(xmRow + (size_t)t * 12);

    lif<700, 512, false>(WT1, xm32, mk[0], m1, alpha, nullptr, tid, lane, wv);
    lif<512, 256, false>(WT2, (const unsigned*)mk[0], mk[1], m2, alpha, nullptr,
                         tid, lane, wv);
    lif<256, 128, false>(WT3, (const unsigned*)mk[1], mk[0], m3, alpha, nullptr,
                         tid, lane, wv);
    lif<128, 256, false>(WT4, (const unsigned*)mk[0], mk[1], m4, alpha, nullptr,
                         tid, lane, wv);
    lif<256, 512, false>(WT5, (const unsigned*)mk[1], mk[0], m5, alpha, nullptr,
                         tid, lane, wv);
    lif<512, 700, true>(WT6, (const unsigned*)mk[0], nullptr, m6, alpha,
                        outRowBase + (size_t)t * kNin, tid, lane, wv);
  }
}

}  // namespace

extern "C" void kernel_launch(void* const* d_in, const int* in_sizes, int n_in,
                              void* d_out, int out_size, void* d_ws, size_t ws_size,
                              hipStream_t stream) {
  const float* x = (const float*)d_in[0];
  float* ws = (float*)d_ws;
  unsigned long long* xm = (unsigned long long*)d_ws + XM_OFF_U64;
  float* out = (float*)d_out;

  // Transpose all weights into workspace: dst[K][H] = W[H][K]^T.
  struct TK { int H, K; size_t off; int idx; };
  const TK tk[6] = {
      {512, 700, OFF1, 1},  // W_ih1
      {256, 512, OFF2, 2},  // W_h1h2
      {128, 256, OFF3, 3},  // W_h2h3
      {256, 128, OFF4, 4},  // W_h3h2
      {512, 256, OFF5, 5},  // W_h2h1
      {700, 512, OFF6, 6},  // W_h1o
  };
  for (int i = 0; i < 6; ++i) {
    const int n = tk[i].H * tk[i].K;
    transpose_k<<<(n + 255) / 256, 256, 0, stream>>>(
        (const float*)d_in[tk[i].idx], ws + tk[i].off, tk[i].H, tk[i].K);
  }

  // Precompute input spike bitmasks for all (row, t).
  xmask_k<<<512 * kWin, 256, 0, stream>>>(x, xm);

  snn_main<<<512, 704, 0, stream>>>(ws, xm, out);
}

// Round 4
// 2507.121 us; speedup vs baseline: 1.1286x; 1.1286x over previous
//
#include <hip/hip_runtime.h>
#include <cmath>

namespace {

constexpr int kWin = 100;
constexpr int kNin = 700;

// f64 transposed-weight offsets (in doubles) inside d_ws.
constexpr size_t OFF1 = 0;        // WT1 [700][512]
constexpr size_t OFF2 = 358400;   // WT2 [512][256]
constexpr size_t OFF3 = 489472;   // WT3 [256][128]
constexpr size_t OFF4 = 522240;   // WT4 [128][256]
constexpr size_t OFF5 = 555008;   // WT5 [256][512]
constexpr size_t OFF6 = 686080;   // WT6 [512][700]
// total 1,044,480 doubles = 8.36 MB

__global__ void transpose_k(const float* __restrict__ src, double* __restrict__ dst,
                            int H, int K) {
  int idx = blockIdx.x * blockDim.x + threadIdx.x;
  if (idx < H * K) {
    int h = idx / K;
    int k = idx - h * K;
    dst[(size_t)k * H + h] = (double)src[idx];  // dst[K][H] = f64(src[H][K]^T)
  }
}

// Scatter phase: wave w (w < NW) writes the active-neuron offsets of mask word
// w into listOut at its exclusive-prefix position. Entries are pre-multiplied
// by MULT (= H of the consuming layer) so the gather needs no per-column mul.
// Deterministic: list order == ascending neuron index.
template <int NW, int MULT>
__device__ __forceinline__ void scatter(const unsigned long long* words,
                                        const int* cnts, int* listOut,
                                        int* cntTotal, int w, int lane) {
  if (w < NW) {
    int c[12];
    {
      const int4 ca = *(const int4*)(cnts + 0);
      c[0] = ca.x; c[1] = ca.y; c[2] = ca.z; c[3] = ca.w;
    }
    if (NW > 4) {
      const int4 cb = *(const int4*)(cnts + 4);
      c[4] = cb.x; c[5] = cb.y; c[6] = cb.z; c[7] = cb.w;
    }
    if (NW > 8) {
      const int4 cc = *(const int4*)(cnts + 8);
      c[8] = cc.x; c[9] = cc.y; c[10] = cc.z; c[11] = cc.w;
    }
    int base = 0;
#pragma unroll
    for (int i = 0; i + 1 < NW; ++i)
      if (w > i) base += c[i];
    const unsigned long long word = words[w];
    const unsigned long long lt = ((unsigned long long)1 << lane) - 1ull;
    if ((word >> lane) & 1ull)
      listOut[base + (int)__popcll(word & lt)] = (w * 64 + lane) * MULT;
    if (w == NW - 1 && lane == 0) *cntTotal = base + c[NW - 1];
  }
}

// One LIF layer:
//  gather: kp = tid>>8 sums its contiguous quarter of the active-column list
//          (f64 weights, 2 interleaved accumulators, fixed order) for output
//          slots h = s*256 + (tid&255); partials -> LDS.
//  SYNC1 (inside), then combine: wave w owns h = w*64+lane; sums the 4
//  partials in fixed order, membrane update, spike, ballot -> words/cnts.
// mem_new = mem*alpha + sum(active WT cols); spike = mem_new > 0.3;
// mem = (mem_new < 0.3) ? mem_new : 0.  ((1-o_spike) is redundant: the hard
// reset already zeroed spiking neurons; VRESET = 0.)
template <int H, bool OUT>
__device__ __forceinline__ void layer(const double* __restrict__ WT,
                                      const int* __restrict__ listIn, int cntIn,
                                      double* __restrict__ partsBuf,
                                      unsigned long long* words, int* cnts,
                                      double& mem, double alpha,
                                      float* __restrict__ outRow,
                                      int kp, int ht, int w, int lane) {
  constexpr int NS = (H + 255) / 256;
  constexpr int BIAS = (NS == 3) ? 256 : 0;  // keeps slot offsets in ±4095B imm
  {
    double a0[NS], a1[NS];
#pragma unroll
    for (int s = 0; s < NS; ++s) { a0[s] = 0.0; a1[s] = 0.0; }
    const int qlen = ((cntIn + 15) >> 4) << 2;  // 4-aligned quarter
    const int start = kp * qlen;
    const int e0 = start + qlen;
    const int end = (e0 < cntIn) ? e0 : cntIn;
    const double* __restrict__ base = WT + ht + BIAS;
    int j = start;
#pragma unroll 1
    for (; j + 4 <= end; j += 4) {
      const int4 e = *(const int4*)(listIn + j);
      const double* p0 = base + e.x;
      const double* p1 = base + e.y;
      const double* p2 = base + e.z;
      const double* p3 = base + e.w;
#pragma unroll
      for (int s = 0; s < NS; ++s) {
        const int o = s * 256 - BIAS;
        const double f0 = p0[o];
        const double f1 = p1[o];
        const double f2 = p2[o];
        const double f3 = p3[o];
        a0[s] += f0; a1[s] += f1; a0[s] += f2; a1[s] += f3;
      }
    }
    for (; j < end; ++j) {
      const double* p0 = base + listIn[j];
#pragma unroll
      for (int s = 0; s < NS; ++s) a0[s] += p0[s * 256 - BIAS];
    }
#pragma unroll
    for (int s = 0; s < NS; ++s)
      partsBuf[(kp * NS + s) * 256 + ht] = a0[s] + a1[s];
  }
  __syncthreads();  // SYNC1: partials ready
  if (w * 64 < H) {  // wave-uniform
    const int h = w * 64 + lane;
    bool sp = false;
    if (h < H) {
      const int s = h >> 8;
      const int hh = h & 255;
      const double p0 = partsBuf[(0 * NS + s) * 256 + hh];
      const double p1 = partsBuf[(1 * NS + s) * 256 + hh];
      const double p2 = partsBuf[(2 * NS + s) * 256 + hh];
      const double p3 = partsBuf[(3 * NS + s) * 256 + hh];
      const double sum = (p0 + p1) + (p2 + p3);
      const double mm = mem * alpha + sum;
      sp = (mm > 0.3);
      mem = (mm < 0.3) ? mm : 0.0;
      if (OUT) outRow[h] = sp ? 1.0f : 0.0f;
    }
    if (!OUT) {
      const unsigned long long b = __ballot(sp);
      if (lane == 0) {
        words[w] = b;
        cnts[w] = (int)__popcll(b);
      }
    }
  }
}

// 512 blocks x 1024 threads, one batch row per block. The 5 zero-padded
// warm-up steps provably keep all state at 0 and are skipped.
__global__ __launch_bounds__(1024, 8) void snn_main(
    const float* __restrict__ x, const double* __restrict__ wsd,
    float* __restrict__ out) {
  const int tid = threadIdx.x;
  const int lane = tid & 63;
  const int w = tid >> 6;   // wave 0..15
  const int kp = tid >> 8;  // gather quarter 0..3
  const int ht = tid & 255;
  const int row = blockIdx.x;

  const double* WT1 = wsd + OFF1;
  const double* WT2 = wsd + OFF2;
  const double* WT3 = wsd + OFF3;
  const double* WT4 = wsd + OFF4;
  const double* WT5 = wsd + OFF5;
  const double* WT6 = wsd + OFF6;

  __shared__ alignas(16) double parts0[4 * 3 * 256];  // 24 KB
  __shared__ alignas(16) double parts1[4 * 3 * 256];  // 24 KB
  __shared__ alignas(16) int listA[704];
  __shared__ alignas(16) int listB[704];
  __shared__ alignas(16) unsigned long long words[12];
  __shared__ alignas(16) int cnts[12];
  __shared__ int cntT;

  // Thread owns neuron h = w*64+lane of every layer (where h < H).
  double m1 = 0.0, m2 = 0.0, m3 = 0.0, m4 = 0.0, m5 = 0.0, m6 = 0.0;
  const double alpha = exp(-1.0 / 3.0);

  const int hOwn = w * 64 + lane;
  const bool xOwn = (hOwn < kNin);
  const float* xRow = x + (size_t)row * kWin * kNin;
  float* outBase = out + (size_t)row * kWin * kNin;

  // Prologue: compact x[0] into listA; prefetch x[1].
  float xv = xOwn ? xRow[hOwn] : 0.0f;
  if (w < 11) {
    const bool px = xOwn && (xv != 0.0f);
    const unsigned long long b = __ballot(px);
    if (lane == 0) { words[w] = b; cnts[w] = (int)__popcll(b); }
  }
  __syncthreads();
  scatter<11, 512>(words, cnts, listA, &cntT, w, lane);
  __syncthreads();
  int cntX = __builtin_amdgcn_readfirstlane(cntT);
  if (xOwn) xv = xRow[(size_t)1 * kNin + hOwn];

  for (int t = 0; t < kWin; ++t) {
    int c;
    // L1: listA -> parts0 -> listB
    layer<512, false>(WT1, listA, cntX, parts0, words, cnts, m1, alpha, nullptr,
                      kp, ht, w, lane);
    __syncthreads();
    scatter<8, 256>(words, cnts, listB, &cntT, w, lane);
    __syncthreads();
    c = __builtin_amdgcn_readfirstlane(cntT);
    // L2: listB -> parts1 -> listA
    layer<256, false>(WT2, listB, c, parts1, words, cnts, m2, alpha, nullptr,
                      kp, ht, w, lane);
    __syncthreads();
    scatter<4, 128>(words, cnts, listA, &cntT, w, lane);
    __syncthreads();
    c = __builtin_amdgcn_readfirstlane(cntT);
    // L3: listA -> parts0 -> listB
    layer<128, false>(WT3, listA, c, parts0, words, cnts, m3, alpha, nullptr,
                      kp, ht, w, lane);
    __syncthreads();
    scatter<2, 256>(words, cnts, listB, &cntT, w, lane);
    __syncthreads();
    c = __builtin_amdgcn_readfirstlane(cntT);
    // L4: listB -> parts1 -> listA
    layer<256, false>(WT4, listB, c, parts1, words, cnts, m4, alpha, nullptr,
                      kp, ht, w, lane);
    __syncthreads();
    scatter<4, 512>(words, cnts, listA, &cntT, w, lane);
    __syncthreads();
    c = __builtin_amdgcn_readfirstlane(cntT);
    // L5: listA -> parts0 -> listB
    layer<512, false>(WT5, listA, c, parts0, words, cnts, m5, alpha, nullptr,
                      kp, ht, w, lane);
    __syncthreads();
    scatter<8, 700>(words, cnts, listB, &cntT, w, lane);
    __syncthreads();
    c = __builtin_amdgcn_readfirstlane(cntT);
    // L6 (output): listB -> parts1 -> out; fold next step's input compaction
    // into this phase (words were last read before L5's closing barrier).
    layer<700, true>(WT6, listB, c, parts1, words, cnts, m6, alpha,
                     outBase + (size_t)t * kNin, kp, ht, w, lane);
    if (w < 11) {
      const bool px = xOwn && (xv != 0.0f);  // xv == x[t+1]
      const unsigned long long b = __ballot(px);
      if (lane == 0) { words[w] = b; cnts[w] = (int)__popcll(b); }
    }
    __syncthreads();
    scatter<11, 512>(words, cnts, listA, &cntT, w, lane);
    __syncthreads();
    cntX = __builtin_amdgcn_readfirstlane(cntT);
    const int tn = (t + 2 < kWin) ? (t + 2) : (kWin - 1);
    if (xOwn) xv = xRow[(size_t)tn * kNin + hOwn];  // prefetch 2 steps ahead
  }
}

}  // namespace

extern "C" void kernel_launch(void* const* d_in, const int* in_sizes, int n_in,
                              void* d_out, int out_size, void* d_ws, size_t ws_size,
                              hipStream_t stream) {
  const float* x = (const float*)d_in[0];
  double* ws = (double*)d_ws;
  float* out = (float*)d_out;

  // Transpose+widen all weights into workspace: dst[K][H] = f64(W[H][K]^T).
  struct TK { int H, K; size_t off; int idx; };
  const TK tk[6] = {
      {512, 700, OFF1, 1},  // W_ih1
      {256, 512, OFF2, 2},  // W_h1h2
      {128, 256, OFF3, 3},  // W_h2h3
      {256, 128, OFF4, 4},  // W_h3h2
      {512, 256, OFF5, 5},  // W_h2h1
      {700, 512, OFF6, 6},  // W_h1o
  };
  for (int i = 0; i < 6; ++i) {
    const int n = tk[i].H * tk[i].K;
    transpose_k<<<(n + 255) / 256, 256, 0, stream>>>(
        (const float*)d_in[tk[i].idx], ws + tk[i].off, tk[i].H, tk[i].K);
  }

  snn_main<<<512, 1024, 0, stream>>>(x, ws, out);
}